// Round 2
// baseline (161.538 us; speedup 1.0000x reference)
//
#include <hip/hip_runtime.h>
#include <stdint.h>

typedef __attribute__((ext_vector_type(8))) __bf16 bf16x8;
typedef __attribute__((ext_vector_type(4))) float f32x4;

#define MFMA16(a, b, c) __builtin_amdgcn_mfma_f32_16x16x32_bf16((a), (b), (c), 0, 0, 0)

__device__ __forceinline__ uint16_t f2b(float f) {
    union { float f; uint32_t u; } v; v.f = f;
    uint32_t u = v.u;
    return (uint16_t)((u + 0x7FFFu + ((u >> 16) & 1u)) >> 16);
}

__device__ __forceinline__ bf16x8 ldb8(const uint16_t* p) {
    return *(const bf16x8*)p;
}

// ---------------------------------------------------------------------------
// Kernel 0: pack weights to bf16.  Wall[320][256] = [Wq;Wk;Wv], ball[320],
// Wobf[256][512].
// ---------------------------------------------------------------------------
__global__ void pack_kernel(const float* __restrict__ Wq, const float* __restrict__ Wk,
                            const float* __restrict__ Wv, const float* __restrict__ bq,
                            const float* __restrict__ bk, const float* __restrict__ bv,
                            const float* __restrict__ Wo,
                            uint16_t* __restrict__ Wall, uint16_t* __restrict__ Wobf,
                            float* __restrict__ ball) {
    int i = blockIdx.x * blockDim.x + threadIdx.x;
    int stride = gridDim.x * blockDim.x;
    for (int idx = i; idx < 320 * 256; idx += stride) {
        int r = idx >> 8, c = idx & 255;
        float v = (r < 32) ? Wq[r * 256 + c]
                 : (r < 64) ? Wk[(r - 32) * 256 + c]
                            : Wv[(r - 64) * 256 + c];
        Wall[idx] = f2b(v);
    }
    for (int idx = i; idx < 256 * 512; idx += stride) Wobf[idx] = f2b(Wo[idx]);
    for (int idx = i; idx < 320; idx += stride)
        ball[idx] = (idx < 32) ? bq[idx] : (idx < 64) ? bk[idx - 32] : bv[idx - 64];
}

// ---------------------------------------------------------------------------
// Kernel 1: QKV projection.
// grid 256 = b(4) x ntile(64).  Emits qt[b][n][32], kt[b][n][32] (transposed,
// k-contiguous) and v[b][c][n] (c-major), all bf16.
// ---------------------------------------------------------------------------
__global__ __launch_bounds__(256) void qkv_kernel(
    const float* __restrict__ x, const uint16_t* __restrict__ Wall,
    const float* __restrict__ ball, uint16_t* __restrict__ qtg,
    uint16_t* __restrict__ ktg, uint16_t* __restrict__ vg) {
    __shared__ uint16_t xt[64][264];   // [n_local][c], pad 264

    const int b = blockIdx.x >> 6;
    const int n0 = (blockIdx.x & 63) * 64;
    const int t = threadIdx.x;
    const float* xb = x + (size_t)b * 256 * 4096;

    {
        const int nPart = t & 15, cIdx = t >> 4;
#pragma unroll
        for (int rep = 0; rep < 16; rep++) {
            int c = rep * 16 + cIdx;
            float4 f = *(const float4*)(xb + (size_t)c * 4096 + n0 + nPart * 4);
            xt[nPart * 4 + 0][c] = f2b(f.x);
            xt[nPart * 4 + 1][c] = f2b(f.y);
            xt[nPart * 4 + 2][c] = f2b(f.z);
            xt[nPart * 4 + 3][c] = f2b(f.w);
        }
    }
    __syncthreads();

    const int w = t >> 6, lane = t & 63, l15 = lane & 15, g = lane >> 4;

    // --- qk: D[n(64), o(64)], wave w owns m-tile w ---
    f32x4 accqk[4] = {};
#pragma unroll
    for (int ks = 0; ks < 8; ks++) {
        bf16x8 af = ldb8(&xt[w * 16 + l15][ks * 32 + g * 8]);
#pragma unroll
        for (int ot = 0; ot < 4; ot++) {
            bf16x8 bfr = ldb8(Wall + (ot * 16 + l15) * 256 + ks * 32 + g * 8);
            accqk[ot] = MFMA16(af, bfr, accqk[ot]);
        }
    }
#pragma unroll
    for (int ot = 0; ot < 4; ot++) {
        int o = ot * 16 + l15;
        float bias = ball[o];
#pragma unroll
        for (int r = 0; r < 4; r++) {
            int n = n0 + w * 16 + g * 4 + r;
            float v = accqk[ot][r] + bias;
            if (ot < 2) qtg[((size_t)b * 4096 + n) * 32 + o] = f2b(v);
            else        ktg[((size_t)b * 4096 + n) * 32 + (o - 32)] = f2b(v);
        }
    }

    // --- v: D[o(256), n(64)], wave w owns o-tiles 4w..4w+3 ---
    f32x4 accv[4][4] = {};
#pragma unroll
    for (int ks = 0; ks < 8; ks++) {
        bf16x8 av[4], bv4[4];
#pragma unroll
        for (int mt = 0; mt < 4; mt++)
            av[mt] = ldb8(Wall + (64 + (w * 4 + mt) * 16 + l15) * 256 + ks * 32 + g * 8);
#pragma unroll
        for (int nt = 0; nt < 4; nt++)
            bv4[nt] = ldb8(&xt[nt * 16 + l15][ks * 32 + g * 8]);
#pragma unroll
        for (int mt = 0; mt < 4; mt++)
#pragma unroll
            for (int nt = 0; nt < 4; nt++)
                accv[mt][nt] = MFMA16(av[mt], bv4[nt], accv[mt][nt]);
    }
#pragma unroll
    for (int mt = 0; mt < 4; mt++) {
#pragma unroll
        for (int r = 0; r < 4; r++) {
            int o = (w * 4 + mt) * 16 + g * 4 + r;
            float bias = ball[64 + o];
#pragma unroll
            for (int nt = 0; nt < 4; nt++) {
                int n = n0 + nt * 16 + l15;
                vg[((size_t)b * 256 + o) * 4096 + n] = f2b(accv[mt][nt][r] + bias);
            }
        }
    }
}

// ---------------------------------------------------------------------------
// Kernel 2: flash attention v2.
// grid 256 = b(4) x mtile(64), XCD-swizzled; 512 threads (8 waves).
// Waves 0-3: S^T producers (16 m-rows each) via MFMA(K,Q); all 8 waves: PV on
// a 32-channel c-slice.  Double-buffered swizzled LDS for P (2x8KB) and V
// (2x32KB); K frags direct from global, prefetched; 1 barrier per chunk.
// Max-free softmax (logits bounded); row sums accumulated per-lane (S^T makes
// lane own row m=l15), reduced once at the end.
// ---------------------------------------------------------------------------
__global__ __launch_bounds__(512, 2) void attn_kernel(
    const uint16_t* __restrict__ qtg, const uint16_t* __restrict__ ktg,
    const uint16_t* __restrict__ vg, uint16_t* __restrict__ og) {
    __shared__ uint16_t vts[2][256][64];   // [buf][c][n] 16B-block-swizzled
    __shared__ uint16_t pts[2][64][64];    // [buf][m][n] 16B-block-swizzled
    __shared__ float ls[64];

    const int bid = blockIdx.x;
    const int swz = (bid & 7) * 32 + (bid >> 3);   // XCD-chunked (256%8==0)
    const int b = swz >> 6;
    const int m0 = (swz & 63) * 64;
    const int t = threadIdx.x, w = t >> 6, lane = t & 63, l15 = lane & 15, g = lane >> 4;

    const uint16_t* qb = qtg + (size_t)b * 4096 * 32;
    const uint16_t* kb = ktg + (size_t)b * 4096 * 32;
    const uint16_t* vb = vg  + (size_t)b * 256 * 4096;

    // V staging geometry: pass i covers rows i*64..i*64+63; thread -> (row,col)
    const int crow = t >> 3;                         // 0..63
    const int jcol = (t & 7) * 8;                    // element col within chunk
    const int jswz = ((t & 7) ^ (crow & 7)) * 16;    // swizzled byte col
    const int rdblk = l15 & 7;                       // read-side xor key

    // Q fragment (waves 4-7 alias w&3's row; value unused there)
    const bf16x8 qf = ldb8(qb + (size_t)(m0 + (w & 3) * 16 + l15) * 32 + g * 8);

    f32x4 acc[4][2] = {};      // [m-tile][c-tile] of O[64, 32w..32w+31]
    float lpart = 0.f;

    uint4 vreg[4];
    auto issueV = [&](int ch) {
        const uint16_t* s0 = vb + (size_t)ch * 64 + jcol;
#pragma unroll
        for (int i = 0; i < 4; i++)
            vreg[i] = *(const uint4*)(s0 + (size_t)(i * 64 + crow) * 4096);
    };
    auto writeV = [&](int q) {
        char* base = (char*)&vts[q][0][0];
#pragma unroll
        for (int i = 0; i < 4; i++)
            *(uint4*)(base + (i * 64 + crow) * 128 + jswz) = vreg[i];
    };
    auto loadK = [&](int ch, bf16x8* kf) {
#pragma unroll
        for (int nt = 0; nt < 4; nt++)
            kf[nt] = ldb8(kb + (size_t)(ch * 64 + nt * 16 + l15) * 32 + g * 8);
    };
    auto sphase = [&](int p, const bf16x8* kf) {
        char* base = (char*)&pts[p][0][0] + (w * 16 + l15) * 128;
#pragma unroll
        for (int nt = 0; nt < 4; nt++) {
            f32x4 z = {};
            f32x4 s = MFMA16(kf[nt], qf, z);   // S^T: lane: n=nt*16+4g+r, m=w*16+l15
            float e0 = __expf(s[0]), e1 = __expf(s[1]);
            float e2 = __expf(s[2]), e3 = __expf(s[3]);
            lpart += (e0 + e1) + (e2 + e3);
            uint2 d;
            d.x = (uint32_t)f2b(e0) | ((uint32_t)f2b(e1) << 16);
            d.y = (uint32_t)f2b(e2) | ((uint32_t)f2b(e3) << 16);
            *(uint2*)(base + ((nt * 32 + 8 * g) ^ (rdblk << 4))) = d;
        }
    };
    auto pv = [&](int p) {
        const char* pbase = (const char*)&pts[p][0][0];
        const char* vbase = (const char*)&vts[p][0][0];
        __builtin_amdgcn_s_setprio(1);
#pragma unroll
        for (int ks = 0; ks < 2; ks++) {
            const int blk = ((ks * 4 + g) ^ rdblk) << 4;
            bf16x8 pa[4], vf[2];
#pragma unroll
            for (int mt = 0; mt < 4; mt++)
                pa[mt] = ldb8((const uint16_t*)(pbase + (mt * 16 + l15) * 128 + blk));
#pragma unroll
            for (int ct = 0; ct < 2; ct++)
                vf[ct] = ldb8((const uint16_t*)(vbase + (w * 32 + ct * 16 + l15) * 128 + blk));
#pragma unroll
            for (int mt = 0; mt < 4; mt++)
#pragma unroll
                for (int ct = 0; ct < 2; ct++)
                    acc[mt][ct] = MFMA16(pa[mt], vf[ct], acc[mt][ct]);
        }
        __builtin_amdgcn_s_setprio(0);
    };

    bf16x8 kfA[4], kfB[4];
    issueV(0);
    if (w < 4) loadK(0, kfA);
    writeV(0);
    issueV(1);

    for (int ch = 0; ch < 64; ch += 2) {
        // ---- even chunk (buffers 0) ----
        if (w < 4) sphase(0, kfA);
        __syncthreads();
        writeV(1);                          // V(ch+1) -> buf1
        if (ch + 2 < 64) issueV(ch + 2);
        if (w < 4) loadK(ch + 1, kfB);
        pv(0);
        // ---- odd chunk (buffers 1) ----
        if (w < 4) sphase(1, kfB);
        __syncthreads();
        if (ch + 2 < 64) {
            writeV(0);                      // V(ch+2) -> buf0
            if (ch + 3 < 64) issueV(ch + 3);
            if (w < 4) loadK(ch + 2, kfA);
        }
        pv(1);
    }

    // row-sum finish: reduce over g (lane bits 4,5), publish, scale
    if (w < 4) {
        lpart += __shfl_xor(lpart, 16);
        lpart += __shfl_xor(lpart, 32);
        if (lane < 16) ls[w * 16 + lane] = lpart;
    }
    __syncthreads();

#pragma unroll
    for (int mt = 0; mt < 4; mt++)
#pragma unroll
        for (int r = 0; r < 4; r++) {
            const int m = mt * 16 + g * 4 + r;
            const float rinv = 1.0f / ls[m];
            const size_t rowo = ((size_t)b * 4096 + m0 + m) * 256;
#pragma unroll
            for (int ct = 0; ct < 2; ct++)
                og[rowo + w * 32 + ct * 16 + l15] = f2b(acc[mt][ct][r] * rinv);
        }
}

// ---------------------------------------------------------------------------
// Kernel 3: y = Wo[:, :256] @ out + Wo[:, 256:] @ x + bo.
// ---------------------------------------------------------------------------
__global__ __launch_bounds__(256) void out_kernel(
    const float* __restrict__ x, const uint16_t* __restrict__ og,
    const uint16_t* __restrict__ Wobf, const float* __restrict__ bo,
    float* __restrict__ y) {
    __shared__ uint16_t xt[64][264];

    const int b = blockIdx.x >> 6;
    const int m0 = (blockIdx.x & 63) * 64;
    const int t = threadIdx.x;
    const float* xb = x + (size_t)b * 256 * 4096;

    {
        const int nPart = t & 15, cIdx = t >> 4;
#pragma unroll
        for (int rep = 0; rep < 16; rep++) {
            int c = rep * 16 + cIdx;
            float4 f = *(const float4*)(xb + (size_t)c * 4096 + m0 + nPart * 4);
            xt[nPart * 4 + 0][c] = f2b(f.x);
            xt[nPart * 4 + 1][c] = f2b(f.y);
            xt[nPart * 4 + 2][c] = f2b(f.z);
            xt[nPart * 4 + 3][c] = f2b(f.w);
        }
    }
    __syncthreads();

    const int w = t >> 6, lane = t & 63, l15 = lane & 15, g = lane >> 4;
    const uint16_t* ob = og + ((size_t)b * 4096 + m0) * 256;

    f32x4 acc[4][4] = {};
#pragma unroll
    for (int ks = 0; ks < 8; ks++) {
        bf16x8 af[4], bfr[4];
#pragma unroll
        for (int mt = 0; mt < 4; mt++)
            af[mt] = ldb8(Wobf + ((w * 4 + mt) * 16 + l15) * 512 + ks * 32 + g * 8);
#pragma unroll
        for (int nt = 0; nt < 4; nt++)
            bfr[nt] = ldb8(ob + (size_t)(nt * 16 + l15) * 256 + ks * 32 + g * 8);
#pragma unroll
        for (int mt = 0; mt < 4; mt++)
#pragma unroll
            for (int nt = 0; nt < 4; nt++)
                acc[mt][nt] = MFMA16(af[mt], bfr[nt], acc[mt][nt]);
    }
#pragma unroll
    for (int ks = 0; ks < 8; ks++) {
        bf16x8 af[4], bfr[4];
#pragma unroll
        for (int mt = 0; mt < 4; mt++)
            af[mt] = ldb8(Wobf + ((w * 4 + mt) * 16 + l15) * 512 + 256 + ks * 32 + g * 8);
#pragma unroll
        for (int nt = 0; nt < 4; nt++)
            bfr[nt] = ldb8(&xt[nt * 16 + l15][ks * 32 + g * 8]);
#pragma unroll
        for (int mt = 0; mt < 4; mt++)
#pragma unroll
            for (int nt = 0; nt < 4; nt++)
                acc[mt][nt] = MFMA16(af[mt], bfr[nt], acc[mt][nt]);
    }

#pragma unroll
    for (int mt = 0; mt < 4; mt++)
#pragma unroll
        for (int r = 0; r < 4; r++) {
            int o = (w * 4 + mt) * 16 + g * 4 + r;
            float bias = bo[o];
#pragma unroll
            for (int nt = 0; nt < 4; nt++) {
                int m = m0 + nt * 16 + l15;
                y[((size_t)b * 256 + o) * 4096 + m] = acc[mt][nt][r] + bias;
            }
        }
}

// ---------------------------------------------------------------------------
extern "C" void kernel_launch(void* const* d_in, const int* in_sizes, int n_in,
                              void* d_out, int out_size, void* d_ws, size_t ws_size,
                              hipStream_t stream) {
    const float* x  = (const float*)d_in[0];
    const float* Wq = (const float*)d_in[1];
    const float* bq = (const float*)d_in[2];
    const float* Wk = (const float*)d_in[3];
    const float* bk = (const float*)d_in[4];
    const float* Wv = (const float*)d_in[5];
    const float* bv = (const float*)d_in[6];
    const float* Wo = (const float*)d_in[7];
    const float* bo = (const float*)d_in[8];
    float* y = (float*)d_out;

    char* ws = (char*)d_ws;
    uint16_t* Wall = (uint16_t*)(ws + 0);          // 163840 B
    uint16_t* Wobf = (uint16_t*)(ws + 163840);     // 262144 B
    float*    ball = (float*)(ws + 425984);        // 1280 B
    uint16_t* qtg  = (uint16_t*)(ws + 427520);     // 1 MiB
    uint16_t* ktg  = (uint16_t*)(ws + 1476096);    // 1 MiB
    uint16_t* vgw  = (uint16_t*)(ws + 2524672);    // 8 MiB
    uint16_t* ogw  = (uint16_t*)(ws + 10913280);   // 8 MiB

    pack_kernel<<<256, 256, 0, stream>>>(Wq, Wk, Wv, bq, bk, bv, Wo, Wall, Wobf, ball);
    qkv_kernel<<<256, 256, 0, stream>>>(x, Wall, ball, qtg, ktg, vgw);
    attn_kernel<<<256, 512, 0, stream>>>(qtg, ktg, vgw, ogw);
    out_kernel<<<256, 256, 0, stream>>>(x, ogw, Wobf, bo, y);
}

// Round 3
// 139.130 us; speedup vs baseline: 1.1611x; 1.1611x over previous
//
#include <hip/hip_runtime.h>
#include <stdint.h>

typedef __attribute__((ext_vector_type(8))) __bf16 bf16x8;
typedef __attribute__((ext_vector_type(4))) float f32x4;
typedef __attribute__((ext_vector_type(16))) float f32x16;

#define MFMA16(a, b, c) __builtin_amdgcn_mfma_f32_16x16x32_bf16((a), (b), (c), 0, 0, 0)
#define MFMA32(a, b, c) __builtin_amdgcn_mfma_f32_32x32x16_bf16((a), (b), (c), 0, 0, 0)

__device__ __forceinline__ uint16_t f2b(float f) {
    union { float f; uint32_t u; } v; v.f = f;
    uint32_t u = v.u;
    return (uint16_t)((u + 0x7FFFu + ((u >> 16) & 1u)) >> 16);
}

__device__ __forceinline__ bf16x8 ldb8(const uint16_t* p) {
    return *(const bf16x8*)p;
}

// ---------------------------------------------------------------------------
// Kernel 0: pack weights to bf16.  Wall[320][256] = [Wq;Wk;Wv], ball[320],
// Wobf[256][512].
// ---------------------------------------------------------------------------
__global__ void pack_kernel(const float* __restrict__ Wq, const float* __restrict__ Wk,
                            const float* __restrict__ Wv, const float* __restrict__ bq,
                            const float* __restrict__ bk, const float* __restrict__ bv,
                            const float* __restrict__ Wo,
                            uint16_t* __restrict__ Wall, uint16_t* __restrict__ Wobf,
                            float* __restrict__ ball) {
    int i = blockIdx.x * blockDim.x + threadIdx.x;
    int stride = gridDim.x * blockDim.x;
    for (int idx = i; idx < 320 * 256; idx += stride) {
        int r = idx >> 8, c = idx & 255;
        float v = (r < 32) ? Wq[r * 256 + c]
                 : (r < 64) ? Wk[(r - 32) * 256 + c]
                            : Wv[(r - 64) * 256 + c];
        Wall[idx] = f2b(v);
    }
    for (int idx = i; idx < 256 * 512; idx += stride) Wobf[idx] = f2b(Wo[idx]);
    for (int idx = i; idx < 320; idx += stride)
        ball[idx] = (idx < 32) ? bq[idx] : (idx < 64) ? bk[idx - 32] : bv[idx - 64];
}

// ---------------------------------------------------------------------------
// Kernel 1: QKV projection.
// grid 256 = b(4) x ntile(64).  Emits qt[b][n][32], kt[b][n][32] (transposed,
// k-contiguous) and v[b][c][n] (c-major), all bf16.
// ---------------------------------------------------------------------------
__global__ __launch_bounds__(256) void qkv_kernel(
    const float* __restrict__ x, const uint16_t* __restrict__ Wall,
    const float* __restrict__ ball, uint16_t* __restrict__ qtg,
    uint16_t* __restrict__ ktg, uint16_t* __restrict__ vg) {
    __shared__ uint16_t xt[64][264];   // [n_local][c], pad 264

    const int b = blockIdx.x >> 6;
    const int n0 = (blockIdx.x & 63) * 64;
    const int t = threadIdx.x;
    const float* xb = x + (size_t)b * 256 * 4096;

    {
        const int nPart = t & 15, cIdx = t >> 4;
#pragma unroll
        for (int rep = 0; rep < 16; rep++) {
            int c = rep * 16 + cIdx;
            float4 f = *(const float4*)(xb + (size_t)c * 4096 + n0 + nPart * 4);
            xt[nPart * 4 + 0][c] = f2b(f.x);
            xt[nPart * 4 + 1][c] = f2b(f.y);
            xt[nPart * 4 + 2][c] = f2b(f.z);
            xt[nPart * 4 + 3][c] = f2b(f.w);
        }
    }
    __syncthreads();

    const int w = t >> 6, lane = t & 63, l15 = lane & 15, g = lane >> 4;

    // --- qk: D[n(64), o(64)], wave w owns m-tile w ---
    f32x4 accqk[4] = {};
#pragma unroll
    for (int ks = 0; ks < 8; ks++) {
        bf16x8 af = ldb8(&xt[w * 16 + l15][ks * 32 + g * 8]);
#pragma unroll
        for (int ot = 0; ot < 4; ot++) {
            bf16x8 bfr = ldb8(Wall + (ot * 16 + l15) * 256 + ks * 32 + g * 8);
            accqk[ot] = MFMA16(af, bfr, accqk[ot]);
        }
    }
#pragma unroll
    for (int ot = 0; ot < 4; ot++) {
        int o = ot * 16 + l15;
        float bias = ball[o];
#pragma unroll
        for (int r = 0; r < 4; r++) {
            int n = n0 + w * 16 + g * 4 + r;
            float v = accqk[ot][r] + bias;
            if (ot < 2) qtg[((size_t)b * 4096 + n) * 32 + o] = f2b(v);
            else        ktg[((size_t)b * 4096 + n) * 32 + (o - 32)] = f2b(v);
        }
    }

    // --- v: D[o(256), n(64)], wave w owns o-tiles 4w..4w+3 ---
    f32x4 accv[4][4] = {};
#pragma unroll
    for (int ks = 0; ks < 8; ks++) {
        bf16x8 av[4], bv4[4];
#pragma unroll
        for (int mt = 0; mt < 4; mt++)
            av[mt] = ldb8(Wall + (64 + (w * 4 + mt) * 16 + l15) * 256 + ks * 32 + g * 8);
#pragma unroll
        for (int nt = 0; nt < 4; nt++)
            bv4[nt] = ldb8(&xt[nt * 16 + l15][ks * 32 + g * 8]);
#pragma unroll
        for (int mt = 0; mt < 4; mt++)
#pragma unroll
            for (int nt = 0; nt < 4; nt++)
                accv[mt][nt] = MFMA16(av[mt], bv4[nt], accv[mt][nt]);
    }
#pragma unroll
    for (int mt = 0; mt < 4; mt++) {
#pragma unroll
        for (int r = 0; r < 4; r++) {
            int o = (w * 4 + mt) * 16 + g * 4 + r;
            float bias = ball[64 + o];
#pragma unroll
            for (int nt = 0; nt < 4; nt++) {
                int n = n0 + nt * 16 + l15;
                vg[((size_t)b * 256 + o) * 4096 + n] = f2b(accv[mt][nt][r] + bias);
            }
        }
    }
}

// ---------------------------------------------------------------------------
// Kernel 2: flash attention v3 — barrier-free, LDS-free (32x32x16 MFMA).
// grid 256 = b(4) x mtile(64), XCD-swizzled; 256 threads (4 waves).
// Each wave: ALL 64 m-rows x its own 64-channel slice (c-split: V read once
// per block).  S^T = MFMA(K, Q): lane (l31,hi) owns row m=mt*32+l31; exp &
// row-sum lane-local (max-free softmax, logits bounded).  P->A-frag via one
// shfl_xor(32) pair per 16-n window.  K/V frags from global (L2/L1), double
// buffered in regs, KVBLK=32.  No __syncthreads in the loop; LDS = 1KB
// row-sum broadcast in epilogue only.
// ---------------------------------------------------------------------------
__global__ __launch_bounds__(256, 2) void attn_kernel(
    const uint16_t* __restrict__ qtg, const uint16_t* __restrict__ ktg,
    const uint16_t* __restrict__ vg, uint16_t* __restrict__ og) {
    __shared__ float ls[4][64];

    const int bid = blockIdx.x;
    const int swz = (bid & 7) * 32 + (bid >> 3);   // XCD-chunked (256%8==0)
    const int b = swz >> 6;
    const int m0 = (swz & 63) * 64;
    const int t = threadIdx.x, w = t >> 6, lane = t & 63;
    const int l31 = lane & 31, hi = lane >> 5;

    const uint16_t* qb = qtg + (size_t)b * 4096 * 32;
    const uint16_t* kb = ktg + (size_t)b * 4096 * 32;
    const uint16_t* vb = vg  + (size_t)b * 256 * 4096;

    // Q fragments: qf[mt][ks] = Q[m0+mt*32+l31][ks*16+hi*8 ..+8]
    bf16x8 qf[2][2];
#pragma unroll
    for (int mt = 0; mt < 2; mt++)
#pragma unroll
        for (int ks = 0; ks < 2; ks++)
            qf[mt][ks] = ldb8(qb + (size_t)(m0 + mt * 32 + l31) * 32 + ks * 16 + hi * 8);

    const uint16_t* kbase = kb + l31 * 32 + hi * 8;
    const uint16_t* vbase = vb + (size_t)(w * 64 + l31) * 4096 + hi * 8;

    f32x16 acc[2][2] = {};     // [mt][ct]: O[m0+mt*32+rows][w*64+ct*32+l31]
    float lpart[2] = {0.f, 0.f};

    auto loadK = [&](int ch, bf16x8* kf) {
#pragma unroll
        for (int ks = 0; ks < 2; ks++)
            kf[ks] = ldb8(kbase + ch * 1024 + ks * 16);
    };
    auto loadV = [&](int ch, bf16x8 (*vf)[2]) {
#pragma unroll
        for (int ct = 0; ct < 2; ct++)
#pragma unroll
            for (int ks = 0; ks < 2; ks++)
                vf[ct][ks] = ldb8(vbase + (size_t)ct * 32 * 4096 + ch * 32 + ks * 16);
    };

    auto step = [&](const bf16x8* kf, const bf16x8 (*vf)[2]) {
        bf16x8 paf[2][2];
#pragma unroll
        for (int mt = 0; mt < 2; mt++) {
            f32x16 z = {};
            f32x16 s = MFMA32(kf[0], qf[mt][0], z);
            s = MFMA32(kf[1], qf[mt][1], s);
            // lane (l31,hi) reg r: n = (r&3)+8*(r>>2)+4*hi, m = mt*32+l31
            float e[16];
#pragma unroll
            for (int r = 0; r < 16; r++) e[r] = __expf(s[r]);
            float sum = 0.f;
#pragma unroll
            for (int r = 0; r < 16; r++) sum += e[r];
            lpart[mt] += sum;
#pragma unroll
            for (int ks = 0; ks < 2; ks++) {
                uint32_t pk0 = (uint32_t)f2b(e[8 * ks + 0]) | ((uint32_t)f2b(e[8 * ks + 1]) << 16);
                uint32_t pk1 = (uint32_t)f2b(e[8 * ks + 2]) | ((uint32_t)f2b(e[8 * ks + 3]) << 16);
                uint32_t pk2 = (uint32_t)f2b(e[8 * ks + 4]) | ((uint32_t)f2b(e[8 * ks + 5]) << 16);
                uint32_t pk3 = (uint32_t)f2b(e[8 * ks + 6]) | ((uint32_t)f2b(e[8 * ks + 7]) << 16);
                uint32_t g0 = hi ? pk0 : pk2;
                uint32_t g1 = hi ? pk1 : pk3;
                uint32_t r0 = (uint32_t)__shfl_xor((int)g0, 32);
                uint32_t r1 = (uint32_t)__shfl_xor((int)g1, 32);
                union { bf16x8 v; uint32_t d[4]; } u;
                if (hi == 0) { u.d[0] = pk0; u.d[1] = pk1; u.d[2] = r0;  u.d[3] = r1; }
                else         { u.d[0] = r0;  u.d[1] = r1;  u.d[2] = pk2; u.d[3] = pk3; }
                paf[mt][ks] = u.v;
            }
        }
#pragma unroll
        for (int ks = 0; ks < 2; ks++)
#pragma unroll
            for (int mt = 0; mt < 2; mt++)
#pragma unroll
                for (int ct = 0; ct < 2; ct++)
                    acc[mt][ct] = MFMA32(paf[mt][ks], vf[ct][ks], acc[mt][ct]);
    };

    bf16x8 kfA[2], kfB[2], vfA[2][2], vfB[2][2];
    loadK(0, kfA); loadV(0, vfA);
    loadK(1, kfB); loadV(1, vfB);

    for (int ch = 0; ch < 128; ch += 2) {
        step(kfA, vfA);
        if (ch + 2 < 128) { loadK(ch + 2, kfA); loadV(ch + 2, vfA); }
        step(kfB, vfB);
        if (ch + 3 < 128) { loadK(ch + 3, kfB); loadV(ch + 3, vfB); }
    }

    // row-sum broadcast (lane l31 holds sum for m = mt*32+l31)
#pragma unroll
    for (int mt = 0; mt < 2; mt++) {
        float rs = lpart[mt] + __shfl_xor(lpart[mt], 32);
        if (hi == 0) ls[w][mt * 32 + l31] = 1.0f / rs;
    }
    __syncthreads();

#pragma unroll
    for (int mt = 0; mt < 2; mt++)
#pragma unroll
        for (int r = 0; r < 16; r++) {
            const int rowm = (r & 3) + 8 * (r >> 2) + 4 * hi;
            const float rinv = ls[w][mt * 32 + rowm];
            const size_t rowo = ((size_t)b * 4096 + m0 + mt * 32 + rowm) * 256 + w * 64 + l31;
#pragma unroll
            for (int ct = 0; ct < 2; ct++)
                og[rowo + ct * 32] = f2b(acc[mt][ct][r] * rinv);
        }
}

// ---------------------------------------------------------------------------
// Kernel 3: y = Wo[:, :256] @ out + Wo[:, 256:] @ x + bo.
// ---------------------------------------------------------------------------
__global__ __launch_bounds__(256) void out_kernel(
    const float* __restrict__ x, const uint16_t* __restrict__ og,
    const uint16_t* __restrict__ Wobf, const float* __restrict__ bo,
    float* __restrict__ y) {
    __shared__ uint16_t xt[64][264];

    const int b = blockIdx.x >> 6;
    const int m0 = (blockIdx.x & 63) * 64;
    const int t = threadIdx.x;
    const float* xb = x + (size_t)b * 256 * 4096;

    {
        const int nPart = t & 15, cIdx = t >> 4;
#pragma unroll
        for (int rep = 0; rep < 16; rep++) {
            int c = rep * 16 + cIdx;
            float4 f = *(const float4*)(xb + (size_t)c * 4096 + m0 + nPart * 4);
            xt[nPart * 4 + 0][c] = f2b(f.x);
            xt[nPart * 4 + 1][c] = f2b(f.y);
            xt[nPart * 4 + 2][c] = f2b(f.z);
            xt[nPart * 4 + 3][c] = f2b(f.w);
        }
    }
    __syncthreads();

    const int w = t >> 6, lane = t & 63, l15 = lane & 15, g = lane >> 4;
    const uint16_t* ob = og + ((size_t)b * 4096 + m0) * 256;

    f32x4 acc[4][4] = {};
#pragma unroll
    for (int ks = 0; ks < 8; ks++) {
        bf16x8 af[4], bfr[4];
#pragma unroll
        for (int mt = 0; mt < 4; mt++)
            af[mt] = ldb8(Wobf + ((w * 4 + mt) * 16 + l15) * 512 + ks * 32 + g * 8);
#pragma unroll
        for (int nt = 0; nt < 4; nt++)
            bfr[nt] = ldb8(ob + (size_t)(nt * 16 + l15) * 256 + ks * 32 + g * 8);
#pragma unroll
        for (int mt = 0; mt < 4; mt++)
#pragma unroll
            for (int nt = 0; nt < 4; nt++)
                acc[mt][nt] = MFMA16(af[mt], bfr[nt], acc[mt][nt]);
    }
#pragma unroll
    for (int ks = 0; ks < 8; ks++) {
        bf16x8 af[4], bfr[4];
#pragma unroll
        for (int mt = 0; mt < 4; mt++)
            af[mt] = ldb8(Wobf + ((w * 4 + mt) * 16 + l15) * 512 + 256 + ks * 32 + g * 8);
#pragma unroll
        for (int nt = 0; nt < 4; nt++)
            bfr[nt] = ldb8(&xt[nt * 16 + l15][ks * 32 + g * 8]);
#pragma unroll
        for (int mt = 0; mt < 4; mt++)
#pragma unroll
            for (int nt = 0; nt < 4; nt++)
                acc[mt][nt] = MFMA16(af[mt], bfr[nt], acc[mt][nt]);
    }

#pragma unroll
    for (int mt = 0; mt < 4; mt++)
#pragma unroll
        for (int r = 0; r < 4; r++) {
            int o = (w * 4 + mt) * 16 + g * 4 + r;
            float bias = bo[o];
#pragma unroll
            for (int nt = 0; nt < 4; nt++) {
                int m = m0 + nt * 16 + l15;
                y[((size_t)b * 256 + o) * 4096 + m] = acc[mt][nt][r] + bias;
            }
        }
}

// ---------------------------------------------------------------------------
extern "C" void kernel_launch(void* const* d_in, const int* in_sizes, int n_in,
                              void* d_out, int out_size, void* d_ws, size_t ws_size,
                              hipStream_t stream) {
    const float* x  = (const float*)d_in[0];
    const float* Wq = (const float*)d_in[1];
    const float* bq = (const float*)d_in[2];
    const float* Wk = (const float*)d_in[3];
    const float* bk = (const float*)d_in[4];
    const float* Wv = (const float*)d_in[5];
    const float* bv = (const float*)d_in[6];
    const float* Wo = (const float*)d_in[7];
    const float* bo = (const float*)d_in[8];
    float* y = (float*)d_out;

    char* ws = (char*)d_ws;
    uint16_t* Wall = (uint16_t*)(ws + 0);          // 163840 B
    uint16_t* Wobf = (uint16_t*)(ws + 163840);     // 262144 B
    float*    ball = (float*)(ws + 425984);        // 1280 B
    uint16_t* qtg  = (uint16_t*)(ws + 427520);     // 1 MiB
    uint16_t* ktg  = (uint16_t*)(ws + 1476096);    // 1 MiB
    uint16_t* vgw  = (uint16_t*)(ws + 2524672);    // 8 MiB
    uint16_t* ogw  = (uint16_t*)(ws + 10913280);   // 8 MiB

    pack_kernel<<<256, 256, 0, stream>>>(Wq, Wk, Wv, bq, bk, bv, Wo, Wall, Wobf, ball);
    qkv_kernel<<<256, 256, 0, stream>>>(x, Wall, ball, qtg, ktg, vgw);
    attn_kernel<<<256, 256, 0, stream>>>(qtg, ktg, vgw, ogw);
    out_kernel<<<256, 256, 0, stream>>>(x, ogw, Wobf, bo, y);
}